// Round 1
// baseline (3033.514 us; speedup 1.0000x reference)
//
#include <hip/hip_runtime.h>
#include <math.h>

#define NB 2
#define C1 128
#define C2 256
#define HH 128
#define WW 128
#define NPIX (HH*WW)
#define NHEADS 8
#define DH 16
#define NG 8
#define CPG 16

__device__ __forceinline__ float sigmoidf_(float v) { return 1.f / (1.f + expf(-v)); }

// ---------------- concat [y, x] -> cat ----------------
__global__ __launch_bounds__(256) void concat_k(const float* __restrict__ y,
                                                const float* __restrict__ x,
                                                float* __restrict__ cat) {
  int idx = blockIdx.x * 256 + threadIdx.x;
  const int per_b = C2 * NPIX / 4;
  const int total = NB * per_b;
  if (idx >= total) return;
  int b = idx / per_b;
  int rem = idx - b * per_b;
  int c = rem / (NPIX / 4);
  int n4 = rem - c * (NPIX / 4);
  float4 val;
  if (c < C1) val = ((const float4*)y)[((size_t)b * C1 + c) * (NPIX / 4) + n4];
  else        val = ((const float4*)x)[((size_t)b * C1 + (c - C1)) * (NPIX / 4) + n4];
  ((float4*)cat)[idx] = val;
}

// ---------------- 1x1 conv as GEMM: out[b,m,n] = sum_k w[m,k] * f(in[b,k,n]) ----------------
template<bool RELU_IN, bool BIAS>
__global__ __launch_bounds__(256) void conv1x1_k(const float* __restrict__ in,
                                                 const float* __restrict__ w,
                                                 const float* __restrict__ bias,
                                                 float* __restrict__ out,
                                                 int Cin, int Cout) {
  __shared__ float As[16][64];
  __shared__ float Bs[16][68];
  int b = blockIdx.z;
  int m0 = blockIdx.y * 64, n0 = blockIdx.x * 64;
  int tid = threadIdx.x;
  int tx = tid & 15, ty = tid >> 4;
  float acc[4][4];
#pragma unroll
  for (int i = 0; i < 4; i++)
#pragma unroll
    for (int j = 0; j < 4; j++) acc[i][j] = 0.f;
  const float* inb = in + (size_t)b * Cin * NPIX;
  for (int k0 = 0; k0 < Cin; k0 += 16) {
#pragma unroll
    for (int i = 0; i < 4; i++) {
      int e = tid + i * 256;
      int k = e >> 6, m = e & 63;
      As[k][m] = w[(size_t)(m0 + m) * Cin + k0 + k];
      float v = inb[(size_t)(k0 + k) * NPIX + n0 + m];
      if (RELU_IN) v = fmaxf(v, 0.f);
      Bs[k][m] = v;
    }
    __syncthreads();
#pragma unroll
    for (int k = 0; k < 16; k++) {
      float4 a4 = *(const float4*)&As[k][ty * 4];
      float4 b4 = *(const float4*)&Bs[k][tx * 4];
      float av[4] = {a4.x, a4.y, a4.z, a4.w};
      float bv[4] = {b4.x, b4.y, b4.z, b4.w};
#pragma unroll
      for (int i = 0; i < 4; i++)
#pragma unroll
        for (int j = 0; j < 4; j++) acc[i][j] += av[i] * bv[j];
    }
    __syncthreads();
  }
#pragma unroll
  for (int i = 0; i < 4; i++) {
    int m = m0 + ty * 4 + i;
    float bvv = BIAS ? bias[m] : 0.f;
    float4 o4 = make_float4(acc[i][0] + bvv, acc[i][1] + bvv, acc[i][2] + bvv, acc[i][3] + bvv);
    *(float4*)&out[((size_t)b * Cout + m) * NPIX + n0 + tx * 4] = o4;
  }
}

// ---------------- depthwise 3x3, pad=1, on 128x128 ----------------
__global__ __launch_bounds__(256) void dw3x3_k(const float* __restrict__ in,
                                               const float* __restrict__ w,
                                               float* __restrict__ out, int Cc) {
  int idx = blockIdx.x * 256 + threadIdx.x;
  int total = NB * Cc * NPIX;
  if (idx >= total) return;
  int n = idx & (NPIX - 1);
  int bc = idx >> 14;  // NPIX = 16384 = 2^14
  int c = bc % Cc;
  int yy = n >> 7, xx = n & 127;
  const float* p = in + (size_t)bc * NPIX;
  const float* wc = w + c * 9;
  float acc = 0.f;
#pragma unroll
  for (int ky = 0; ky < 3; ky++) {
    int iy = yy + ky - 1;
    if (iy < 0 || iy >= HH) continue;
#pragma unroll
    for (int kx = 0; kx < 3; kx++) {
      int ix = xx + kx - 1;
      if (ix < 0 || ix >= WW) continue;
      acc += wc[ky * 3 + kx] * p[iy * WW + ix];
    }
  }
  out[idx] = acc;
}

// ---------------- avgpool 2x2 on cat (128->64) ----------------
__global__ __launch_bounds__(256) void avgpool_k(const float* __restrict__ in,
                                                 float* __restrict__ out) {
  int idx = blockIdx.x * 256 + threadIdx.x;
  int total = NB * C2 * 64 * 64;
  if (idx >= total) return;
  int xo = idx & 63;
  int yo = (idx >> 6) & 63;
  int bc = idx >> 12;
  const float* p = in + (size_t)bc * NPIX + (yo * 2) * WW + xo * 2;
  out[idx] = 0.25f * (p[0] + p[1] + p[WW] + p[WW + 1]);
}

// ---------------- direct 3x3 conv, 32x32 tile, 4-px strips ----------------
template<int OCPB, bool GATE, int PAD>
__global__ __launch_bounds__(256) void conv3x3_k(const float* __restrict__ in,
                                                 const float* __restrict__ w,
                                                 const float* __restrict__ ga,
                                                 float* __restrict__ out,
                                                 int Cin, int Cout, int Hi, int Wi,
                                                 int Ho, int Wo) {
  const int CHUNK = 8;
  __shared__ float s_in[CHUNK][34][36];
  __shared__ float s_w[CHUNK][OCPB][12];
  int b = blockIdx.z;
  int oc0 = blockIdx.y * OCPB;
  int tiles_x = (Wo + 31) >> 5;
  int tiy = blockIdx.x / tiles_x, tix = blockIdx.x % tiles_x;
  int ty0 = tiy * 32, tx0 = tix * 32;
  int tid = threadIdx.x;
  int row = tid >> 3;       // 0..31
  int sx = (tid & 7) * 4;   // 0..28
  int gy = ty0 + row;
  int gx0 = tx0 + sx;
  const int HiWi = Hi * Wi;
  const int HoWo = Ho * Wo;
  const float* inb = in + (size_t)b * Cin * HiWi;
  float acc[OCPB][4];
#pragma unroll
  for (int o = 0; o < OCPB; o++)
#pragma unroll
    for (int j = 0; j < 4; j++) acc[o][j] = 0.f;

  for (int c0 = 0; c0 < Cin; c0 += CHUNK) {
    for (int e = tid; e < CHUNK * 34 * 36; e += 256) {
      int c = e / (34 * 36);
      int r = (e / 36) % 34;
      int col = e % 36;
      int iy = ty0 - PAD + r;
      int ix = tx0 - PAD + col;
      float v = 0.f;
      if (col < 34 && iy >= 0 && iy < Hi && ix >= 0 && ix < Wi)
        v = inb[(size_t)(c0 + c) * HiWi + iy * Wi + ix];
      s_in[c][r][col] = v;
    }
    for (int e = tid; e < CHUNK * OCPB * 9; e += 256) {
      int c = e / (OCPB * 9);
      int o = (e / 9) % OCPB;
      int t = e % 9;
      s_w[c][o][t] = w[((size_t)(oc0 + o) * Cin + c0 + c) * 9 + t];
    }
    __syncthreads();
#pragma unroll 2
    for (int c = 0; c < CHUNK; c++) {
      float vr[3][7];
#pragma unroll
      for (int ky = 0; ky < 3; ky++) {
        float4 ra = *(const float4*)&s_in[c][row + ky][sx];
        float4 rb = *(const float4*)&s_in[c][row + ky][sx + 4];
        vr[ky][0] = ra.x; vr[ky][1] = ra.y; vr[ky][2] = ra.z; vr[ky][3] = ra.w;
        vr[ky][4] = rb.x; vr[ky][5] = rb.y; vr[ky][6] = rb.z;
      }
#pragma unroll
      for (int o = 0; o < OCPB; o++) {
        float4 wa = *(const float4*)&s_w[c][o][0];
        float4 wb = *(const float4*)&s_w[c][o][4];
        float w8 = s_w[c][o][8];
        float wt[9] = {wa.x, wa.y, wa.z, wa.w, wb.x, wb.y, wb.z, wb.w, w8};
#pragma unroll
        for (int j = 0; j < 4; j++) {
          float s = acc[o][j];
#pragma unroll
          for (int ky = 0; ky < 3; ky++)
#pragma unroll
            for (int kx = 0; kx < 3; kx++)
              s += wt[ky * 3 + kx] * vr[ky][j + kx];
          acc[o][j] = s;
        }
      }
    }
    __syncthreads();
  }
  if (gy < Ho) {
#pragma unroll
    for (int o = 0; o < OCPB; o++) {
      int oc = oc0 + o;
#pragma unroll
      for (int j = 0; j < 4; j++) {
        int gx = gx0 + j;
        if (gx < Wo) {
          float val = acc[o][j];
          if (GATE) {
            int iy = (gy * 62) >> 7;
            int ix = (gx * 62) >> 7;
            float gv = inb[(size_t)oc * HiWi + gy * Wi + gx] +
                       ga[((size_t)b * Cout + oc) * (62 * 62) + iy * 62 + ix];
            val *= sigmoidf_(gv);
          }
          out[((size_t)b * Cout + oc) * HoWo + gy * Wo + gx] = val;
        }
      }
    }
  }
}

// ---------------- modulated deformable conv (k=3, pad=1, groups=8) ----------------
__global__ __launch_bounds__(256) void deform_k(const float* __restrict__ yin,
                                                const float* __restrict__ offs,
                                                const float* __restrict__ dw,
                                                const float* __restrict__ dbias,
                                                float* __restrict__ out) {
  __shared__ float s_w[9][CPG][CPG];  // [t][i][o]
  __shared__ float s_b[CPG];
  int b = blockIdx.z, g = blockIdx.y;
  int tid = threadIdx.x;
  for (int e = tid; e < 9 * CPG * CPG; e += 256) {
    int t = e >> 8;
    int i = (e >> 4) & 15;
    int o = e & 15;
    s_w[t][i][o] = dw[(((size_t)g * CPG + o) * CPG + i) * 9 + t];
  }
  if (tid < CPG) s_b[tid] = dbias[g * CPG + tid];
  __syncthreads();
  int n = blockIdx.x * 256 + tid;
  int yy = n >> 7, xx = n & 127;
  const float* offb = offs + (size_t)b * 18 * NPIX + n;
  const float* inb = yin + ((size_t)b * C1 + g * CPG) * NPIX;
  float4 acc[4];
#pragma unroll
  for (int o4 = 0; o4 < 4; o4++) acc[o4] = make_float4(0.f, 0.f, 0.f, 0.f);

  for (int t = 0; t < 9; t++) {
    float dy = offb[(size_t)(2 * t) * NPIX];
    float dx = offb[(size_t)(2 * t + 1) * NPIX];
    float m = sigmoidf_(offb[(size_t)t * NPIX]);
    float py = (float)(yy - 1 + t / 3) + dy;
    float px = (float)(xx - 1 + t % 3) + dx;
    float y0f = floorf(py), x0f = floorf(px);
    float fy = py - y0f, fx = px - x0f;
    int y0 = (int)y0f, x0 = (int)x0f;
    int y1 = y0 + 1, x1 = x0 + 1;
    float w00 = (1.f - fy) * (1.f - fx) * m;
    float w01 = (1.f - fy) * fx * m;
    float w10 = fy * (1.f - fx) * m;
    float w11 = fy * fx * m;
    bool vy0 = (y0 >= 0 && y0 < HH), vy1 = (y1 >= 0 && y1 < HH);
    bool vx0 = (x0 >= 0 && x0 < WW), vx1 = (x1 >= 0 && x1 < WW);
    if (!(vy0 && vx0)) w00 = 0.f;
    if (!(vy0 && vx1)) w01 = 0.f;
    if (!(vy1 && vx0)) w10 = 0.f;
    if (!(vy1 && vx1)) w11 = 0.f;
    int cy0 = min(max(y0, 0), HH - 1), cy1 = min(max(y1, 0), HH - 1);
    int cx0 = min(max(x0, 0), WW - 1), cx1 = min(max(x1, 0), WW - 1);
    int i00 = cy0 * WW + cx0, i01 = cy0 * WW + cx1;
    int i10 = cy1 * WW + cx0, i11 = cy1 * WW + cx1;
#pragma unroll 4
    for (int i = 0; i < CPG; i++) {
      const float* ch = inb + (size_t)i * NPIX;
      float val = w00 * ch[i00] + w01 * ch[i01] + w10 * ch[i10] + w11 * ch[i11];
      const float4* wrow = (const float4*)&s_w[t][i][0];
#pragma unroll
      for (int o4 = 0; o4 < 4; o4++) {
        float4 wv = wrow[o4];
        acc[o4].x += wv.x * val;
        acc[o4].y += wv.y * val;
        acc[o4].z += wv.z * val;
        acc[o4].w += wv.w * val;
      }
    }
  }
  size_t outbase = ((size_t)b * C1 + g * CPG) * NPIX + n;
#pragma unroll
  for (int o4 = 0; o4 < 4; o4++) {
    float vals[4] = {acc[o4].x, acc[o4].y, acc[o4].z, acc[o4].w};
#pragma unroll
    for (int j = 0; j < 4; j++)
      out[outbase + (size_t)(o4 * 4 + j) * NPIX] = vals[j] + s_b[o4 * 4 + j];
  }
}

// ---------------- zero small accumulators ----------------
__global__ void zero_k(float* p, int n) {
  int i = blockIdx.x * 256 + threadIdx.x;
  if (i < n) p[i] = 0.f;
}

// ---------------- attention: partial Gram + sumsq ----------------
__global__ __launch_bounds__(256) void attn_partial_k(const float* __restrict__ qbuf,
                                                      const float* __restrict__ kvbuf,
                                                      float* __restrict__ s_acc,
                                                      float* __restrict__ qss,
                                                      float* __restrict__ kss) {
  __shared__ float qs[16][129];
  __shared__ float ks[16][129];
  int b = blockIdx.z, h = blockIdx.y, seg = blockIdx.x;
  int tid = threadIdx.x;
  int dd = tid & 15, cc = tid >> 4;
  int n_start = seg * (NPIX / 16);
  float acc = 0.f, q2 = 0.f, k2s = 0.f;
  const float* qb = qbuf + ((size_t)b * C1 + h * DH) * NPIX;
  const float* kb = kvbuf + ((size_t)b * C2 + h * DH) * NPIX;
  for (int n0 = n_start; n0 < n_start + NPIX / 16; n0 += 128) {
    for (int e = tid; e < 16 * 128; e += 256) {
      int r = e >> 7, col = e & 127;
      qs[r][col] = qb[(size_t)r * NPIX + n0 + col];
      ks[r][col] = kb[(size_t)r * NPIX + n0 + col];
    }
    __syncthreads();
#pragma unroll 8
    for (int j = 0; j < 128; j++) {
      float qv = qs[cc][j], kv = ks[dd][j];
      acc += qv * kv;
      q2 += qv * qv;
      k2s += kv * kv;
    }
    __syncthreads();
  }
  int bh = b * NHEADS + h;
  atomicAdd(&s_acc[((size_t)bh * 16 + cc) * 16 + dd], acc);
  if (dd == 0) atomicAdd(&qss[bh * 16 + cc], q2);
  if (cc == 0) atomicAdd(&kss[bh * 16 + dd], k2s);
}

// ---------------- attention: normalize + softmax ----------------
__global__ __launch_bounds__(256) void attn_final_k(const float* __restrict__ s_acc,
                                                    const float* __restrict__ qss,
                                                    const float* __restrict__ kss,
                                                    const float* __restrict__ temp,
                                                    float* __restrict__ attn) {
  __shared__ float S[16][17];
  __shared__ float qn[16], kn[16];
  int bh = blockIdx.x;
  int h = bh % NHEADS;
  int tid = threadIdx.x;
  int dd = tid & 15, cc = tid >> 4;
  if (tid < 16) {
    qn[tid] = fmaxf(sqrtf(qss[bh * 16 + tid]), 1e-12f);
    kn[tid] = fmaxf(sqrtf(kss[bh * 16 + tid]), 1e-12f);
  }
  __syncthreads();
  float t = temp[h];
  float s = s_acc[((size_t)bh * 16 + cc) * 16 + dd] / (qn[cc] * kn[dd]) * t;
  S[cc][dd] = s;
  __syncthreads();
  float mx = -1e30f;
#pragma unroll
  for (int j = 0; j < 16; j++) mx = fmaxf(mx, S[cc][j]);
  float sum = 0.f;
#pragma unroll
  for (int j = 0; j < 16; j++) sum += expf(S[cc][j] - mx);
  attn[((size_t)bh * 16 + cc) * 16 + dd] = expf(s - mx) / sum;
}

// ---------------- attention: out = attn @ v ----------------
__global__ __launch_bounds__(256) void attnout_k(const float* __restrict__ attn,
                                                 const float* __restrict__ kvbuf,
                                                 float* __restrict__ out) {
  __shared__ float s_a[16][16];
  int b = blockIdx.z, h = blockIdx.y;
  int tid = threadIdx.x;
  int bh = b * NHEADS + h;
  s_a[tid >> 4][tid & 15] = attn[((size_t)bh * 16 + (tid >> 4)) * 16 + (tid & 15)];
  __syncthreads();
  int n = blockIdx.x * 256 + tid;
  const float* vb = kvbuf + ((size_t)b * C2 + C1 + h * DH) * NPIX;
  float acc[16];
#pragma unroll
  for (int c = 0; c < 16; c++) acc[c] = 0.f;
#pragma unroll
  for (int d = 0; d < 16; d++) {
    float vv = vb[(size_t)d * NPIX + n];
#pragma unroll
    for (int c = 0; c < 16; c++) acc[c] += s_a[c][d] * vv;
  }
#pragma unroll
  for (int c = 0; c < 16; c++)
    out[((size_t)b * C1 + h * DH + c) * NPIX + n] = acc[c];
}

extern "C" void kernel_launch(void* const* d_in, const int* in_sizes, int n_in,
                              void* d_out, int out_size, void* d_ws, size_t ws_size,
                              hipStream_t stream) {
  const float* x = (const float*)d_in[0];
  const float* y = (const float*)d_in[1];
  const float* q_w = (const float*)d_in[2];
  const float* qd_w = (const float*)d_in[3];
  const float* kv_w = (const float*)d_in[4];
  const float* kvd_w = (const float*)d_in[5];
  const float* proj_w = (const float*)d_in[6];
  const float* temperature = (const float*)d_in[7];
  const float* k2_w = (const float*)d_in[8];
  const float* k3_w = (const float*)d_in[9];
  const float* k4_w = (const float*)d_in[10];
  const float* dcn_w = (const float*)d_in[11];
  const float* dcn_b = (const float*)d_in[12];
  const float* pw_w = (const float*)d_in[13];
  const float* pw_b = (const float*)d_in[14];
  float* out = (float*)d_out;

  char* ws = (char*)d_ws;
  size_t off = 0;
  auto alloc = [&](size_t nf) {
    float* p = (float*)(ws + off);
    off += nf * sizeof(float);
    return p;
  };
  float* CAT = alloc((size_t)NB * C2 * NPIX);
  float* POOL = alloc((size_t)NB * C2 * 64 * 64);
  float* A2 = alloc((size_t)NB * C2 * 62 * 62);
  float* OUT3 = alloc((size_t)NB * C2 * NPIX);
  float* OFFS = alloc((size_t)NB * 18 * NPIX);
  float* TMPA = alloc((size_t)NB * C1 * NPIX);      // q1 -> feat -> attnout
  float* Qb = alloc((size_t)NB * C1 * NPIX);
  float* ALIGNED = alloc((size_t)NB * C1 * NPIX);
  float* SACC = alloc((size_t)NB * NHEADS * 256);
  float* QSS = alloc((size_t)NB * NHEADS * 16);
  float* KSS = alloc((size_t)NB * NHEADS * 16);
  float* ATTN = alloc((size_t)NB * NHEADS * 256);
  float* KV1 = OUT3;  // reuse (out3 dead after k4)
  float* KVb = CAT;   // reuse (cat dead after k3)

  dim3 blk(256);

  // q path
  conv1x1_k<false, false><<<dim3(NPIX / 64, C1 / 64, NB), blk, 0, stream>>>(
      x, q_w, nullptr, TMPA, C1, C1);
  dw3x3_k<<<dim3((NB * C1 * NPIX + 255) / 256), blk, 0, stream>>>(TMPA, qd_w, Qb, C1);

  // offset head
  concat_k<<<dim3((NB * C2 * NPIX / 4 + 255) / 256), blk, 0, stream>>>(y, x, CAT);
  avgpool_k<<<dim3((NB * C2 * 64 * 64 + 255) / 256), blk, 0, stream>>>(CAT, POOL);
  conv3x3_k<4, false, 0><<<dim3(4, C2 / 4, NB), blk, 0, stream>>>(
      POOL, k2_w, nullptr, A2, C2, C2, 64, 64, 62, 62);
  conv3x3_k<8, true, 1><<<dim3(16, C2 / 8, NB), blk, 0, stream>>>(
      CAT, k3_w, A2, OUT3, C2, C2, 128, 128, 128, 128);
  conv3x3_k<3, false, 1><<<dim3(16, 6, NB), blk, 0, stream>>>(
      OUT3, k4_w, nullptr, OFFS, C2, 18, 128, 128, 128, 128);

  // deformable alignment
  deform_k<<<dim3(NPIX / 256, NG, NB), blk, 0, stream>>>(y, OFFS, dcn_w, dcn_b, TMPA);
  conv1x1_k<true, true><<<dim3(NPIX / 64, C1 / 64, NB), blk, 0, stream>>>(
      TMPA, pw_w, pw_b, ALIGNED, C1, C1);

  // kv path
  conv1x1_k<false, false><<<dim3(NPIX / 64, C2 / 64, NB), blk, 0, stream>>>(
      ALIGNED, kv_w, nullptr, KV1, C1, C2);
  dw3x3_k<<<dim3((NB * C2 * NPIX + 255) / 256), blk, 0, stream>>>(KV1, kvd_w, KVb, C2);

  // attention
  zero_k<<<dim3((4608 + 255) / 256), blk, 0, stream>>>(SACC, 4608);
  attn_partial_k<<<dim3(16, NHEADS, NB), blk, 0, stream>>>(Qb, KVb, SACC, QSS, KSS);
  attn_final_k<<<dim3(NB * NHEADS), blk, 0, stream>>>(SACC, QSS, KSS, temperature, ATTN);
  attnout_k<<<dim3(NPIX / 256, NHEADS, NB), blk, 0, stream>>>(ATTN, KVb, TMPA);
  conv1x1_k<false, false><<<dim3(NPIX / 64, C1 / 64, NB), blk, 0, stream>>>(
      TMPA, proj_w, nullptr, out, C1, C1);
}

// Round 2
// 738.149 us; speedup vs baseline: 4.1096x; 4.1096x over previous
//
#include <hip/hip_runtime.h>
#include <math.h>

#define NB 2
#define C1 128
#define C2 256
#define HH 128
#define WW 128
#define NPIX (HH*WW)
#define NHEADS 8
#define DH 16
#define NG 8
#define CPG 16

typedef unsigned short u16;
typedef __attribute__((ext_vector_type(8))) short bf8_t;
typedef __attribute__((ext_vector_type(4))) float f4_t;

__device__ __forceinline__ float sigmoidf_(float v) { return 1.f / (1.f + expf(-v)); }
__device__ __forceinline__ u16 f2bf(float f) {
  unsigned u = __float_as_uint(f);
  return (u16)((u + 0x7FFFu + ((u >> 16) & 1u)) >> 16);
}
__device__ __forceinline__ float bf2f(u16 h) { return __uint_as_float(((unsigned)h) << 16); }

// ---------------- concat [y, x] -> cat ----------------
__global__ __launch_bounds__(256) void concat_k(const float* __restrict__ y,
                                                const float* __restrict__ x,
                                                float* __restrict__ cat) {
  int idx = blockIdx.x * 256 + threadIdx.x;
  const int per_b = C2 * NPIX / 4;
  const int total = NB * per_b;
  if (idx >= total) return;
  int b = idx / per_b;
  int rem = idx - b * per_b;
  int c = rem / (NPIX / 4);
  int n4 = rem - c * (NPIX / 4);
  float4 val;
  if (c < C1) val = ((const float4*)y)[((size_t)b * C1 + c) * (NPIX / 4) + n4];
  else        val = ((const float4*)x)[((size_t)b * C1 + (c - C1)) * (NPIX / 4) + n4];
  ((float4*)cat)[idx] = val;
}

// ---------------- NCHW fp32 -> NHWC bf16 hi/lo split ----------------
template<int CC>
__global__ __launch_bounds__(256) void nhwc_split_k(const float* __restrict__ in,
                                                    u16* __restrict__ oh, u16* __restrict__ ol,
                                                    int NP) {
  __shared__ float tile[64][65];
  int b = blockIdx.z, c0 = blockIdx.y * 64, p0 = blockIdx.x * 64;
  int tid = threadIdx.x;
  for (int e = tid; e < 4096; e += 256) {
    int c = e >> 6, p = e & 63;
    tile[c][p] = in[((size_t)b * CC + c0 + c) * NP + p0 + p];
  }
  __syncthreads();
  for (int e = tid; e < 4096; e += 256) {
    int p = e >> 6, c = e & 63;
    float v = tile[c][p];
    u16 h = f2bf(v);
    u16 l = f2bf(v - bf2f(h));
    size_t o = ((size_t)b * NP + p0 + p) * CC + c0 + c;
    oh[o] = h; ol[o] = l;
  }
}

// ---------------- avgpool2 on CAT -> NHWC bf16 hi/lo (64x64) ----------------
__global__ __launch_bounds__(256) void avgpool_split_k(const float* __restrict__ in,
                                                       u16* __restrict__ oh, u16* __restrict__ ol) {
  __shared__ float tile[64][65];
  int b = blockIdx.z, c0 = blockIdx.y * 64, p0 = blockIdx.x * 64;
  int tid = threadIdx.x;
  for (int e = tid; e < 4096; e += 256) {
    int c = e >> 6, p = e & 63;
    int pp = p0 + p;
    int yo = pp >> 6, xo = pp & 63;
    const float* s = in + ((size_t)b * C2 + c0 + c) * NPIX + yo * 256 + xo * 2;
    tile[c][p] = 0.25f * (s[0] + s[1] + s[WW] + s[WW + 1]);
  }
  __syncthreads();
  for (int e = tid; e < 4096; e += 256) {
    int p = e >> 6, c = e & 63;
    float v = tile[c][p];
    u16 h = f2bf(v);
    u16 l = f2bf(v - bf2f(h));
    size_t o = ((size_t)b * 4096 + p0 + p) * C2 + c0 + c;
    oh[o] = h; ol[o] = l;
  }
}

// ---------------- weight transform: [OC][256][9] -> rows[(t*8+c)*OCR+oc] of [32 hi|32 lo] ----------------
__global__ __launch_bounds__(256) void wtrans_k(const float* __restrict__ w, u16* __restrict__ w2,
                                                int OC, int OCR) {
  int idx = blockIdx.x * 256 + threadIdx.x;
  int total = 9 * 256 * OCR;
  if (idx >= total) return;
  int t = idx / (256 * OCR);
  int rem = idx - t * 256 * OCR;
  int ic = rem / OCR;
  int oc = rem - ic * OCR;
  float v = (oc < OC) ? w[((size_t)oc * 256 + ic) * 9 + t] : 0.f;
  u16 h = f2bf(v);
  u16 l = f2bf(v - bf2f(h));
  size_t row = (size_t)(t * 8 + (ic >> 5)) * OCR + oc;
  w2[row * 64 + (ic & 31)] = h;
  w2[row * 64 + 32 + (ic & 31)] = l;
}

// ---------------- implicit-GEMM 3x3 conv via split-bf16 MFMA ----------------
// Block: 128 px x OCB oc, 4 waves. K = 9 taps x 256 ic (BK=32).
// LDS rows of 64 bf16 = [32 hi|32 lo], 8x 16B slots, XOR swizzle slot^(row&7).
template<int OCB, int WO, int HO, int WI, int HI, int PAD, int OCTOT, int OCR, bool GATE>
__global__ __launch_bounds__(256) void convmfma_k(
    const u16* __restrict__ inH, const u16* __restrict__ inL,
    const u16* __restrict__ w2,
    const float* __restrict__ gA, const float* __restrict__ gB,
    float* __restrict__ outF, u16* __restrict__ outH, u16* __restrict__ outL) {
  constexpr int CIN = 256;
  constexpr int MF = (OCB == 128) ? 4 : 2;
  constexpr int NF = (OCB == 128) ? 4 : 2;
  __shared__ u16 lds_a[128 * 64];
  __shared__ u16 lds_w[OCB * 64];
  char* la = (char*)lds_a;
  char* lw = (char*)lds_w;
  const int b = blockIdx.z;
  const int oc0 = blockIdx.y * OCB;
  const int px0 = blockIdx.x * 128;
  const int tid = threadIdx.x;
  const int lane = tid & 63, wid = tid >> 6;
  const int wpx = (OCB == 128) ? ((wid >> 1) * 64) : (wid * 32);
  const int woc = (OCB == 128) ? ((wid & 1) * 64) : 0;

  // A staging constants: thread stages (px=tid>>1, 16-ic half=tid&1)
  const int spx = tid >> 1;
  const int shalf = tid & 1;
  const int opx = px0 + spx;
  const int py = opx / WO, pxx = opx % WO;
  const bool prow_ok = (opx < HO * WO);
  const int ar7 = spx & 7;
  const int awo0 = spx * 128 + (((shalf * 2 + 0) ^ ar7) << 4);
  const int awo1 = spx * 128 + (((shalf * 2 + 1) ^ ar7) << 4);
  const int awo2 = spx * 128 + (((shalf * 2 + 4) ^ ar7) << 4);
  const int awo3 = spx * 128 + (((shalf * 2 + 5) ^ ar7) << 4);
  // W staging constants: unit = (oc=tid>>1, half=tid&1) covering 32 bf16
  const bool wact = (OCB == 128) ? true : (tid < OCB * 2);
  const int wrow = tid >> 1, whalf = tid & 1;
  int wwo[4];
#pragma unroll
  for (int j = 0; j < 4; j++) wwo[j] = wrow * 128 + (((whalf * 4 + j) ^ (wrow & 7)) << 4);

  // fragment read offsets
  int aoh[MF], aol[MF], woh[NF], wol[NF];
#pragma unroll
  for (int mf = 0; mf < MF; mf++) {
    int r = wpx + mf * 16 + (lane & 15);
    int s = lane >> 4;
    aoh[mf] = r * 128 + ((s ^ (r & 7)) << 4);
    aol[mf] = r * 128 + (((s + 4) ^ (r & 7)) << 4);
  }
#pragma unroll
  for (int nf = 0; nf < NF; nf++) {
    int r = woc + nf * 16 + (lane & 15);
    int s = lane >> 4;
    woh[nf] = r * 128 + ((s ^ (r & 7)) << 4);
    wol[nf] = r * 128 + (((s + 4) ^ (r & 7)) << 4);
  }

  f4_t acc[MF][NF];
#pragma unroll
  for (int mf = 0; mf < MF; mf++)
#pragma unroll
    for (int nf = 0; nf < NF; nf++) { f4_t z = {0.f, 0.f, 0.f, 0.f}; acc[mf][nf] = z; }

  const size_t inb = (size_t)b * (HI * WI) * CIN;
  size_t wg = (size_t)(oc0 + wrow) * 64 + (size_t)whalf * 32;
  for (int t = 0; t < 9; t++) {
    const int iy = py + (t / 3) - PAD;
    const int ix = pxx + (t % 3) - PAD;
    const bool val = prow_ok && iy >= 0 && iy < HI && ix >= 0 && ix < WI;
    const int pixoff = iy * WI + ix;
    for (int c = 0; c < CIN / 32; c++) {
      uint4 ah0 = {0,0,0,0}, ah1 = {0,0,0,0}, al0 = {0,0,0,0}, al1 = {0,0,0,0};
      if (val) {
        size_t a0 = inb + (size_t)pixoff * CIN + c * 32 + shalf * 16;
        const uint4* ph = (const uint4*)(inH + a0);
        const uint4* pl = (const uint4*)(inL + a0);
        ah0 = ph[0]; ah1 = ph[1]; al0 = pl[0]; al1 = pl[1];
      }
      uint4 wv0 = {0,0,0,0}, wv1 = {0,0,0,0}, wv2 = {0,0,0,0}, wv3 = {0,0,0,0};
      if (wact) {
        const uint4* q = (const uint4*)(w2 + wg);
        wv0 = q[0]; wv1 = q[1]; wv2 = q[2]; wv3 = q[3];
      }
      __syncthreads();
      *(uint4*)(la + awo0) = ah0;
      *(uint4*)(la + awo1) = ah1;
      *(uint4*)(la + awo2) = al0;
      *(uint4*)(la + awo3) = al1;
      if (wact) {
        *(uint4*)(lw + wwo[0]) = wv0;
        *(uint4*)(lw + wwo[1]) = wv1;
        *(uint4*)(lw + wwo[2]) = wv2;
        *(uint4*)(lw + wwo[3]) = wv3;
      }
      __syncthreads();
      bf8_t ah[MF], al[MF], wh[NF], wl[NF];
#pragma unroll
      for (int mf = 0; mf < MF; mf++) {
        ah[mf] = *(const bf8_t*)(la + aoh[mf]);
        al[mf] = *(const bf8_t*)(la + aol[mf]);
      }
#pragma unroll
      for (int nf = 0; nf < NF; nf++) {
        wh[nf] = *(const bf8_t*)(lw + woh[nf]);
        wl[nf] = *(const bf8_t*)(lw + wol[nf]);
      }
#pragma unroll
      for (int mf = 0; mf < MF; mf++)
#pragma unroll
        for (int nf = 0; nf < NF; nf++) {
          acc[mf][nf] = __builtin_amdgcn_mfma_f32_16x16x32_bf16(ah[mf], wh[nf], acc[mf][nf], 0, 0, 0);
          acc[mf][nf] = __builtin_amdgcn_mfma_f32_16x16x32_bf16(al[mf], wh[nf], acc[mf][nf], 0, 0, 0);
          acc[mf][nf] = __builtin_amdgcn_mfma_f32_16x16x32_bf16(ah[mf], wl[nf], acc[mf][nf], 0, 0, 0);
        }
      wg += (size_t)OCR * 64;
    }
  }

  // epilogue: D row=(lane>>4)*4+r = px, col=lane&15 = oc  [m89-verified]
#pragma unroll
  for (int mf = 0; mf < MF; mf++) {
    const int pxb = px0 + wpx + mf * 16 + ((lane >> 4) << 2);
#pragma unroll
    for (int nf = 0; nf < NF; nf++) {
      const int oc = oc0 + woc + nf * 16 + (lane & 15);
      if (GATE) {
#pragma unroll
        for (int r = 0; r < 4; r++) {
          const int px = pxb + r;
          const int pyy = px >> 7, px2 = px & 127;
          const int iiy = (pyy * 62) >> 7, iix = (px2 * 62) >> 7;
          float gv = gA[((size_t)b * C2 + oc) * NPIX + px] +
                     gB[((size_t)b * C2 + oc) * 3844 + iiy * 62 + iix];
          float v = acc[mf][nf][r] * sigmoidf_(gv);
          u16 h = f2bf(v);
          u16 l = f2bf(v - bf2f(h));
          size_t o = ((size_t)b * NPIX + px) * C2 + oc;
          outH[o] = h;
          outL[o] = l;
        }
      } else {
        if (pxb < HO * WO && oc < OCTOT) {
          *(f4_t*)&outF[((size_t)b * OCTOT + oc) * (HO * WO) + pxb] = acc[mf][nf];
        }
      }
    }
  }
}

// ---------------- 1x1 conv as GEMM ----------------
template<bool RELU_IN, bool BIAS>
__global__ __launch_bounds__(256) void conv1x1_k(const float* __restrict__ in,
                                                 const float* __restrict__ w,
                                                 const float* __restrict__ bias,
                                                 float* __restrict__ out,
                                                 int Cin, int Cout) {
  __shared__ float As[16][64];
  __shared__ float Bs[16][68];
  int b = blockIdx.z;
  int m0 = blockIdx.y * 64, n0 = blockIdx.x * 64;
  int tid = threadIdx.x;
  int tx = tid & 15, ty = tid >> 4;
  float acc[4][4];
#pragma unroll
  for (int i = 0; i < 4; i++)
#pragma unroll
    for (int j = 0; j < 4; j++) acc[i][j] = 0.f;
  const float* inb = in + (size_t)b * Cin * NPIX;
  for (int k0 = 0; k0 < Cin; k0 += 16) {
#pragma unroll
    for (int i = 0; i < 4; i++) {
      int e = tid + i * 256;
      int k = e >> 6, m = e & 63;
      As[k][m] = w[(size_t)(m0 + m) * Cin + k0 + k];
      float v = inb[(size_t)(k0 + k) * NPIX + n0 + m];
      if (RELU_IN) v = fmaxf(v, 0.f);
      Bs[k][m] = v;
    }
    __syncthreads();
#pragma unroll
    for (int k = 0; k < 16; k++) {
      float4 a4 = *(const float4*)&As[k][ty * 4];
      float4 b4 = *(const float4*)&Bs[k][tx * 4];
      float av[4] = {a4.x, a4.y, a4.z, a4.w};
      float bv[4] = {b4.x, b4.y, b4.z, b4.w};
#pragma unroll
      for (int i = 0; i < 4; i++)
#pragma unroll
        for (int j = 0; j < 4; j++) acc[i][j] += av[i] * bv[j];
    }
    __syncthreads();
  }
#pragma unroll
  for (int i = 0; i < 4; i++) {
    int m = m0 + ty * 4 + i;
    float bvv = BIAS ? bias[m] : 0.f;
    float4 o4 = make_float4(acc[i][0] + bvv, acc[i][1] + bvv, acc[i][2] + bvv, acc[i][3] + bvv);
    *(float4*)&out[((size_t)b * Cout + m) * NPIX + n0 + tx * 4] = o4;
  }
}

// ---------------- depthwise 3x3, pad=1 ----------------
__global__ __launch_bounds__(256) void dw3x3_k(const float* __restrict__ in,
                                               const float* __restrict__ w,
                                               float* __restrict__ out, int Cc) {
  int idx = blockIdx.x * 256 + threadIdx.x;
  int total = NB * Cc * NPIX;
  if (idx >= total) return;
  int n = idx & (NPIX - 1);
  int bc = idx >> 14;
  int c = bc % Cc;
  int yy = n >> 7, xx = n & 127;
  const float* p = in + (size_t)bc * NPIX;
  const float* wc = w + c * 9;
  float acc = 0.f;
#pragma unroll
  for (int ky = 0; ky < 3; ky++) {
    int iy = yy + ky - 1;
    if (iy < 0 || iy >= HH) continue;
#pragma unroll
    for (int kx = 0; kx < 3; kx++) {
      int ix = xx + kx - 1;
      if (ix < 0 || ix >= WW) continue;
      acc += wc[ky * 3 + kx] * p[iy * WW + ix];
    }
  }
  out[idx] = acc;
}

// ---------------- modulated deformable conv ----------------
__global__ __launch_bounds__(256) void deform_k(const float* __restrict__ yin,
                                                const float* __restrict__ offs,
                                                const float* __restrict__ dw,
                                                const float* __restrict__ dbias,
                                                float* __restrict__ out) {
  __shared__ float s_w[9][CPG][CPG];
  __shared__ float s_b[CPG];
  int b = blockIdx.z, g = blockIdx.y;
  int tid = threadIdx.x;
  for (int e = tid; e < 9 * CPG * CPG; e += 256) {
    int t = e >> 8;
    int i = (e >> 4) & 15;
    int o = e & 15;
    s_w[t][i][o] = dw[(((size_t)g * CPG + o) * CPG + i) * 9 + t];
  }
  if (tid < CPG) s_b[tid] = dbias[g * CPG + tid];
  __syncthreads();
  int n = blockIdx.x * 256 + tid;
  int yy = n >> 7, xx = n & 127;
  const float* offb = offs + (size_t)b * 18 * NPIX + n;
  const float* inb = yin + ((size_t)b * C1 + g * CPG) * NPIX;
  float4 acc[4];
#pragma unroll
  for (int o4 = 0; o4 < 4; o4++) acc[o4] = make_float4(0.f, 0.f, 0.f, 0.f);

  for (int t = 0; t < 9; t++) {
    float dy = offb[(size_t)(2 * t) * NPIX];
    float dx = offb[(size_t)(2 * t + 1) * NPIX];
    float m = sigmoidf_(offb[(size_t)t * NPIX]);
    float pyf = (float)(yy - 1 + t / 3) + dy;
    float pxf = (float)(xx - 1 + t % 3) + dx;
    float y0f = floorf(pyf), x0f = floorf(pxf);
    float fy = pyf - y0f, fx = pxf - x0f;
    int y0 = (int)y0f, x0 = (int)x0f;
    int y1 = y0 + 1, x1 = x0 + 1;
    float w00 = (1.f - fy) * (1.f - fx) * m;
    float w01 = (1.f - fy) * fx * m;
    float w10 = fy * (1.f - fx) * m;
    float w11 = fy * fx * m;
    bool vy0 = (y0 >= 0 && y0 < HH), vy1 = (y1 >= 0 && y1 < HH);
    bool vx0 = (x0 >= 0 && x0 < WW), vx1 = (x1 >= 0 && x1 < WW);
    if (!(vy0 && vx0)) w00 = 0.f;
    if (!(vy0 && vx1)) w01 = 0.f;
    if (!(vy1 && vx0)) w10 = 0.f;
    if (!(vy1 && vx1)) w11 = 0.f;
    int cy0 = min(max(y0, 0), HH - 1), cy1 = min(max(y1, 0), HH - 1);
    int cx0 = min(max(x0, 0), WW - 1), cx1 = min(max(x1, 0), WW - 1);
    int i00 = cy0 * WW + cx0, i01 = cy0 * WW + cx1;
    int i10 = cy1 * WW + cx0, i11 = cy1 * WW + cx1;
#pragma unroll 4
    for (int i = 0; i < CPG; i++) {
      const float* ch = inb + (size_t)i * NPIX;
      float val = w00 * ch[i00] + w01 * ch[i01] + w10 * ch[i10] + w11 * ch[i11];
      const float4* wrowp = (const float4*)&s_w[t][i][0];
#pragma unroll
      for (int o4 = 0; o4 < 4; o4++) {
        float4 wv = wrowp[o4];
        acc[o4].x += wv.x * val;
        acc[o4].y += wv.y * val;
        acc[o4].z += wv.z * val;
        acc[o4].w += wv.w * val;
      }
    }
  }
  size_t outbase = ((size_t)b * C1 + g * CPG) * NPIX + n;
#pragma unroll
  for (int o4 = 0; o4 < 4; o4++) {
    float vals[4] = {acc[o4].x, acc[o4].y, acc[o4].z, acc[o4].w};
#pragma unroll
    for (int j = 0; j < 4; j++)
      out[outbase + (size_t)(o4 * 4 + j) * NPIX] = vals[j] + s_b[o4 * 4 + j];
  }
}

// ---------------- zero small accumulators ----------------
__global__ void zero_k(float* p, int n) {
  int i = blockIdx.x * 256 + threadIdx.x;
  if (i < n) p[i] = 0.f;
}

// ---------------- attention: partial Gram + sumsq ----------------
__global__ __launch_bounds__(256) void attn_partial_k(const float* __restrict__ qbuf,
                                                      const float* __restrict__ kvbuf,
                                                      float* __restrict__ s_acc,
                                                      float* __restrict__ qss,
                                                      float* __restrict__ kss) {
  __shared__ float qs[16][129];
  __shared__ float ks[16][129];
  int b = blockIdx.z, h = blockIdx.y, seg = blockIdx.x;
  int tid = threadIdx.x;
  int dd = tid & 15, cc = tid >> 4;
  int n_start = seg * (NPIX / 16);
  float acc = 0.f, q2 = 0.f, k2s = 0.f;
  const float* qb = qbuf + ((size_t)b * C1 + h * DH) * NPIX;
  const float* kb = kvbuf + ((size_t)b * C2 + h * DH) * NPIX;
  for (int n0 = n_start; n0 < n_start + NPIX / 16; n0 += 128) {
    for (int e = tid; e < 16 * 128; e += 256) {
      int r = e >> 7, col = e & 127;
      qs[r][col] = qb[(size_t)r * NPIX + n0 + col];
      ks[r][col] = kb[(size_t)r * NPIX + n0 + col];
    }
    __syncthreads();
#pragma unroll 8
    for (int j = 0; j < 128; j++) {
      float qv = qs[cc][j], kv = ks[dd][j];
      acc += qv * kv;
      q2 += qv * qv;
      k2s += kv * kv;
    }
    __syncthreads();
  }
  int bh = b * NHEADS + h;
  atomicAdd(&s_acc[((size_t)bh * 16 + cc) * 16 + dd], acc);
  if (dd == 0) atomicAdd(&qss[bh * 16 + cc], q2);
  if (cc == 0) atomicAdd(&kss[bh * 16 + dd], k2s);
}

// ---------------- attention: normalize + softmax ----------------
__global__ __launch_bounds__(256) void attn_final_k(const float* __restrict__ s_acc,
                                                    const float* __restrict__ qss,
                                                    const float* __restrict__ kss,
                                                    const float* __restrict__ temp,
                                                    float* __restrict__ attn) {
  __shared__ float S[16][17];
  __shared__ float qn[16], kn[16];
  int bh = blockIdx.x;
  int h = bh % NHEADS;
  int tid = threadIdx.x;
  int dd = tid & 15, cc = tid >> 4;
  if (tid < 16) {
    qn[tid] = fmaxf(sqrtf(qss[bh * 16 + tid]), 1e-12f);
    kn[tid] = fmaxf(sqrtf(kss[bh * 16 + tid]), 1e-12f);
  }
  __syncthreads();
  float t = temp[h];
  float s = s_acc[((size_t)bh * 16 + cc) * 16 + dd] / (qn[cc] * kn[dd]) * t;
  S[cc][dd] = s;
  __syncthreads();
  float mx = -1e30f;
#pragma unroll
  for (int j = 0; j < 16; j++) mx = fmaxf(mx, S[cc][j]);
  float sum = 0.f;
#pragma unroll
  for (int j = 0; j < 16; j++) sum += expf(S[cc][j] - mx);
  attn[((size_t)bh * 16 + cc) * 16 + dd] = expf(s - mx) / sum;
}

// ---------------- attention: out = attn @ v ----------------
__global__ __launch_bounds__(256) void attnout_k(const float* __restrict__ attn,
                                                 const float* __restrict__ kvbuf,
                                                 float* __restrict__ out) {
  __shared__ float s_a[16][16];
  int b = blockIdx.z, h = blockIdx.y;
  int tid = threadIdx.x;
  int bh = b * NHEADS + h;
  s_a[tid >> 4][tid & 15] = attn[((size_t)bh * 16 + (tid >> 4)) * 16 + (tid & 15)];
  __syncthreads();
  int n = blockIdx.x * 256 + tid;
  const float* vb = kvbuf + ((size_t)b * C2 + C1 + h * DH) * NPIX;
  float acc[16];
#pragma unroll
  for (int c = 0; c < 16; c++) acc[c] = 0.f;
#pragma unroll
  for (int d = 0; d < 16; d++) {
    float vv = vb[(size_t)d * NPIX + n];
#pragma unroll
    for (int c = 0; c < 16; c++) acc[c] += s_a[c][d] * vv;
  }
#pragma unroll
  for (int c = 0; c < 16; c++)
    out[((size_t)b * C1 + h * DH + c) * NPIX + n] = acc[c];
}

extern "C" void kernel_launch(void* const* d_in, const int* in_sizes, int n_in,
                              void* d_out, int out_size, void* d_ws, size_t ws_size,
                              hipStream_t stream) {
  const float* x = (const float*)d_in[0];
  const float* y = (const float*)d_in[1];
  const float* q_w = (const float*)d_in[2];
  const float* qd_w = (const float*)d_in[3];
  const float* kv_w = (const float*)d_in[4];
  const float* kvd_w = (const float*)d_in[5];
  const float* proj_w = (const float*)d_in[6];
  const float* temperature = (const float*)d_in[7];
  const float* k2_w = (const float*)d_in[8];
  const float* k3_w = (const float*)d_in[9];
  const float* k4_w = (const float*)d_in[10];
  const float* dcn_w = (const float*)d_in[11];
  const float* dcn_b = (const float*)d_in[12];
  const float* pw_w = (const float*)d_in[13];
  const float* pw_b = (const float*)d_in[14];
  float* out = (float*)d_out;

  char* ws = (char*)d_ws;
  size_t off = 0;
  auto alloc = [&](size_t nbytes) {
    char* p = ws + off;
    off += (nbytes + 255) & ~(size_t)255;
    return p;
  };
  float* CAT = (float*)alloc((size_t)NB * C2 * NPIX * 4);
  u16* CATH = (u16*)alloc((size_t)NB * NPIX * C2 * 2);
  u16* CATL = (u16*)alloc((size_t)NB * NPIX * C2 * 2);
  u16* PH = (u16*)alloc((size_t)NB * 4096 * C2 * 2);
  u16* PL = (u16*)alloc((size_t)NB * 4096 * C2 * 2);
  float* A2 = (float*)alloc((size_t)NB * C2 * 3844 * 4);
  u16* OUT3H = (u16*)alloc((size_t)NB * NPIX * C2 * 2 * 2);  // H then L contiguous
  u16* OUT3L = OUT3H + (size_t)NB * NPIX * C2;
  float* OFFS = (float*)alloc((size_t)NB * 18 * NPIX * 4);
  float* TMPA = (float*)alloc((size_t)NB * C1 * NPIX * 4);
  float* Qb = (float*)alloc((size_t)NB * C1 * NPIX * 4);
  float* ALIGNED = (float*)alloc((size_t)NB * C1 * NPIX * 4);
  u16* W2K2 = (u16*)alloc((size_t)9 * 8 * 256 * 64 * 2);
  u16* W2K3 = (u16*)alloc((size_t)9 * 8 * 256 * 64 * 2);
  u16* W2K4 = (u16*)alloc((size_t)9 * 8 * 32 * 64 * 2);
  float* SACC = (float*)alloc((size_t)NB * NHEADS * 256 * 4 + 512 * 4 + (size_t)NB * NHEADS * 256 * 4);
  float* QSS = SACC + NB * NHEADS * 256;
  float* KSS = QSS + 256;
  float* ATTN = KSS + 256;
  float* KV1 = (float*)OUT3H;  // reuse (dead after k4)
  float* KVb = CAT;            // reuse (dead after k3 gate)

  dim3 blk(256);

  // q path
  conv1x1_k<false, false><<<dim3(NPIX / 64, C1 / 64, NB), blk, 0, stream>>>(
      x, q_w, nullptr, TMPA, C1, C1);
  dw3x3_k<<<dim3((NB * C1 * NPIX + 255) / 256), blk, 0, stream>>>(TMPA, qd_w, Qb, C1);

  // offset head inputs
  concat_k<<<dim3((NB * C2 * NPIX / 4 + 255) / 256), blk, 0, stream>>>(y, x, CAT);
  nhwc_split_k<C2><<<dim3(NPIX / 64, C2 / 64, NB), blk, 0, stream>>>(CAT, CATH, CATL, NPIX);
  avgpool_split_k<<<dim3(4096 / 64, C2 / 64, NB), blk, 0, stream>>>(CAT, PH, PL);
  wtrans_k<<<dim3((9 * 256 * 256 + 255) / 256), blk, 0, stream>>>(k2_w, W2K2, 256, 256);
  wtrans_k<<<dim3((9 * 256 * 256 + 255) / 256), blk, 0, stream>>>(k3_w, W2K3, 256, 256);
  wtrans_k<<<dim3((9 * 256 * 32 + 255) / 256), blk, 0, stream>>>(k4_w, W2K4, 18, 32);

  // k2: pooled 64x64 -> 62x62, pad=0
  convmfma_k<128, 62, 62, 64, 64, 0, 256, 256, false>
      <<<dim3(31, 2, NB), blk, 0, stream>>>(PH, PL, W2K2, nullptr, nullptr, A2, nullptr, nullptr);
  // k3: 128x128 pad=1, gated, writes NHWC hi/lo
  convmfma_k<128, 128, 128, 128, 128, 1, 256, 256, true>
      <<<dim3(128, 2, NB), blk, 0, stream>>>(CATH, CATL, W2K3, CAT, A2, nullptr, OUT3H, OUT3L);
  // k4: -> 18 offset channels (padded to 32)
  convmfma_k<32, 128, 128, 128, 128, 1, 18, 32, false>
      <<<dim3(128, 1, NB), blk, 0, stream>>>(OUT3H, OUT3L, W2K4, nullptr, nullptr, OFFS, nullptr, nullptr);

  // deformable alignment
  deform_k<<<dim3(NPIX / 256, NG, NB), blk, 0, stream>>>(y, OFFS, dcn_w, dcn_b, TMPA);
  conv1x1_k<true, true><<<dim3(NPIX / 64, C1 / 64, NB), blk, 0, stream>>>(
      TMPA, pw_w, pw_b, ALIGNED, C1, C1);

  // kv path
  conv1x1_k<false, false><<<dim3(NPIX / 64, C2 / 64, NB), blk, 0, stream>>>(
      ALIGNED, kv_w, nullptr, KV1, C1, C2);
  dw3x3_k<<<dim3((NB * C2 * NPIX + 255) / 256), blk, 0, stream>>>(KV1, kvd_w, KVb, C2);

  // attention
  zero_k<<<dim3((4608 + 255) / 256), blk, 0, stream>>>(SACC, 4608);
  attn_partial_k<<<dim3(16, NHEADS, NB), blk, 0, stream>>>(Qb, KVb, SACC, QSS, KSS);
  attn_final_k<<<dim3(NB * NHEADS), blk, 0, stream>>>(SACC, QSS, KSS, temperature, ATTN);
  attnout_k<<<dim3(NPIX / 256, NHEADS, NB), blk, 0, stream>>>(ATTN, KVb, TMPA);
  conv1x1_k<false, false><<<dim3(NPIX / 64, C1 / 64, NB), blk, 0, stream>>>(
      TMPA, proj_w, nullptr, out, C1, C1);
}

// Round 3
// 636.388 us; speedup vs baseline: 4.7668x; 1.1599x over previous
//
#include <hip/hip_runtime.h>
#include <math.h>

#define NB 2
#define C1 128
#define C2 256
#define HH 128
#define WW 128
#define NPIX (HH*WW)
#define NHEADS 8
#define DH 16
#define NG 8
#define CPG 16

typedef unsigned short u16;
typedef __attribute__((ext_vector_type(8))) short bf8_t;
typedef __attribute__((ext_vector_type(4))) float f4_t;

__device__ __forceinline__ float sigmoidf_(float v) { return 1.f / (1.f + expf(-v)); }
__device__ __forceinline__ u16 f2bf(float f) {
  unsigned u = __float_as_uint(f);
  return (u16)((u + 0x7FFFu + ((u >> 16) & 1u)) >> 16);
}
__device__ __forceinline__ float bf2f(u16 h) { return __uint_as_float(((unsigned)h) << 16); }

// ---------------- concat [y, x] -> cat ----------------
__global__ __launch_bounds__(256) void concat_k(const float* __restrict__ y,
                                                const float* __restrict__ x,
                                                float* __restrict__ cat) {
  int idx = blockIdx.x * 256 + threadIdx.x;
  const int per_b = C2 * NPIX / 4;
  const int total = NB * per_b;
  if (idx >= total) return;
  int b = idx / per_b;
  int rem = idx - b * per_b;
  int c = rem / (NPIX / 4);
  int n4 = rem - c * (NPIX / 4);
  float4 val;
  if (c < C1) val = ((const float4*)y)[((size_t)b * C1 + c) * (NPIX / 4) + n4];
  else        val = ((const float4*)x)[((size_t)b * C1 + (c - C1)) * (NPIX / 4) + n4];
  ((float4*)cat)[idx] = val;
}

// ---------------- NCHW fp32 -> NHWC bf16 hi/lo split ----------------
template<int CC>
__global__ __launch_bounds__(256) void nhwc_split_k(const float* __restrict__ in,
                                                    u16* __restrict__ oh, u16* __restrict__ ol,
                                                    int NP) {
  __shared__ float tile[64][65];
  int b = blockIdx.z, c0 = blockIdx.y * 64, p0 = blockIdx.x * 64;
  int tid = threadIdx.x;
  for (int e = tid; e < 4096; e += 256) {
    int c = e >> 6, p = e & 63;
    tile[c][p] = in[((size_t)b * CC + c0 + c) * NP + p0 + p];
  }
  __syncthreads();
  for (int e = tid; e < 4096; e += 256) {
    int p = e >> 6, c = e & 63;
    float v = tile[c][p];
    u16 h = f2bf(v);
    u16 l = f2bf(v - bf2f(h));
    size_t o = ((size_t)b * NP + p0 + p) * CC + c0 + c;
    oh[o] = h; ol[o] = l;
  }
}

// ---------------- NCHW fp32 -> NHWC fp32 (for deform gathers) ----------------
__global__ __launch_bounds__(256) void ytrans_k(const float* __restrict__ in,
                                                float* __restrict__ outp) {
  __shared__ float tile[64][65];
  int b = blockIdx.z, c0 = blockIdx.y * 64, p0 = blockIdx.x * 64;
  int tid = threadIdx.x;
  for (int e = tid; e < 4096; e += 256) {
    int c = e >> 6, p = e & 63;
    tile[c][p] = in[((size_t)b * C1 + c0 + c) * NPIX + p0 + p];
  }
  __syncthreads();
  for (int e = tid; e < 4096; e += 256) {
    int p = e >> 6, c = e & 63;
    outp[((size_t)b * NPIX + p0 + p) * C1 + c0 + c] = tile[c][p];
  }
}

// ---------------- avgpool2 on CAT -> NHWC bf16 hi/lo (64x64) ----------------
__global__ __launch_bounds__(256) void avgpool_split_k(const float* __restrict__ in,
                                                       u16* __restrict__ oh, u16* __restrict__ ol) {
  __shared__ float tile[64][65];
  int b = blockIdx.z, c0 = blockIdx.y * 64, p0 = blockIdx.x * 64;
  int tid = threadIdx.x;
  for (int e = tid; e < 4096; e += 256) {
    int c = e >> 6, p = e & 63;
    int pp = p0 + p;
    int yo = pp >> 6, xo = pp & 63;
    const float* s = in + ((size_t)b * C2 + c0 + c) * NPIX + yo * 256 + xo * 2;
    tile[c][p] = 0.25f * (s[0] + s[1] + s[WW] + s[WW + 1]);
  }
  __syncthreads();
  for (int e = tid; e < 4096; e += 256) {
    int p = e >> 6, c = e & 63;
    float v = tile[c][p];
    u16 h = f2bf(v);
    u16 l = f2bf(v - bf2f(h));
    size_t o = ((size_t)b * 4096 + p0 + p) * C2 + c0 + c;
    oh[o] = h; ol[o] = l;
  }
}

// ---------------- weight transform (3x3 convs): rows of [32 hi|32 lo] ----------------
__global__ __launch_bounds__(256) void wtrans_k(const float* __restrict__ w, u16* __restrict__ w2,
                                                int OC, int OCR) {
  int idx = blockIdx.x * 256 + threadIdx.x;
  int total = 9 * 256 * OCR;
  if (idx >= total) return;
  int t = idx / (256 * OCR);
  int rem = idx - t * 256 * OCR;
  int ic = rem / OCR;
  int oc = rem - ic * OCR;
  float v = (oc < OC) ? w[((size_t)oc * 256 + ic) * 9 + t] : 0.f;
  u16 h = f2bf(v);
  u16 l = f2bf(v - bf2f(h));
  size_t row = (size_t)(t * 8 + (ic >> 5)) * OCR + oc;
  w2[row * 64 + (ic & 31)] = h;
  w2[row * 64 + 32 + (ic & 31)] = l;
}

// ---------------- 1x1-conv weight split: [O][Cin] fp32 -> hi/lo bf16 ----------------
__global__ __launch_bounds__(256) void w1trans_k(const float* __restrict__ w,
                                                 u16* __restrict__ wh, u16* __restrict__ wl, int n) {
  int i = blockIdx.x * 256 + threadIdx.x;
  if (i >= n) return;
  float v = w[i];
  u16 h = f2bf(v);
  wh[i] = h;
  wl[i] = f2bf(v - bf2f(h));
}

// ---------------- deform weight prep: dcn_w [128][16][9] -> WD[oc][160] hi/lo ----------------
__global__ __launch_bounds__(256) void wdprep_k(const float* __restrict__ w,
                                                u16* __restrict__ wh, u16* __restrict__ wl) {
  int idx = blockIdx.x * 256 + threadIdx.x;
  if (idx >= 128 * 160) return;
  int oc = idx / 160, k = idx - oc * 160;
  int t = k >> 4, ic = k & 15;
  float v = (t < 9) ? w[((size_t)oc * 16 + ic) * 9 + t] : 0.f;
  u16 h = f2bf(v);
  wh[idx] = h;
  wl[idx] = f2bf(v - bf2f(h));
}

// ---------------- implicit-GEMM 3x3 conv via split-bf16 MFMA (LDS-staged) ----------------
template<int OCB, int WO, int HO, int WI, int HI, int PAD, int OCTOT, int OCR, bool GATE>
__global__ __launch_bounds__(256) void convmfma_k(
    const u16* __restrict__ inH, const u16* __restrict__ inL,
    const u16* __restrict__ w2,
    const float* __restrict__ gA, const float* __restrict__ gB,
    float* __restrict__ outF, u16* __restrict__ outH, u16* __restrict__ outL) {
  constexpr int CIN = 256;
  constexpr int MF = (OCB == 128) ? 4 : 2;
  constexpr int NF = (OCB == 128) ? 4 : 2;
  __shared__ u16 lds_a[128 * 64];
  __shared__ u16 lds_w[OCB * 64];
  char* la = (char*)lds_a;
  char* lw = (char*)lds_w;
  const int b = blockIdx.z;
  const int oc0 = blockIdx.y * OCB;
  const int px0 = blockIdx.x * 128;
  const int tid = threadIdx.x;
  const int lane = tid & 63, wid = tid >> 6;
  const int wpx = (OCB == 128) ? ((wid >> 1) * 64) : (wid * 32);
  const int woc = (OCB == 128) ? ((wid & 1) * 64) : 0;

  const int spx = tid >> 1;
  const int shalf = tid & 1;
  const int opx = px0 + spx;
  const int py = opx / WO, pxx = opx % WO;
  const bool prow_ok = (opx < HO * WO);
  const int ar7 = spx & 7;
  const int awo0 = spx * 128 + (((shalf * 2 + 0) ^ ar7) << 4);
  const int awo1 = spx * 128 + (((shalf * 2 + 1) ^ ar7) << 4);
  const int awo2 = spx * 128 + (((shalf * 2 + 4) ^ ar7) << 4);
  const int awo3 = spx * 128 + (((shalf * 2 + 5) ^ ar7) << 4);
  const bool wact = (OCB == 128) ? true : (tid < OCB * 2);
  const int wrow = tid >> 1, whalf = tid & 1;
  int wwo[4];
#pragma unroll
  for (int j = 0; j < 4; j++) wwo[j] = wrow * 128 + (((whalf * 4 + j) ^ (wrow & 7)) << 4);

  int aoh[MF], aol[MF], woh[NF], wol[NF];
#pragma unroll
  for (int mf = 0; mf < MF; mf++) {
    int r = wpx + mf * 16 + (lane & 15);
    int s = lane >> 4;
    aoh[mf] = r * 128 + ((s ^ (r & 7)) << 4);
    aol[mf] = r * 128 + (((s + 4) ^ (r & 7)) << 4);
  }
#pragma unroll
  for (int nf = 0; nf < NF; nf++) {
    int r = woc + nf * 16 + (lane & 15);
    int s = lane >> 4;
    woh[nf] = r * 128 + ((s ^ (r & 7)) << 4);
    wol[nf] = r * 128 + (((s + 4) ^ (r & 7)) << 4);
  }

  f4_t acc[MF][NF];
#pragma unroll
  for (int mf = 0; mf < MF; mf++)
#pragma unroll
    for (int nf = 0; nf < NF; nf++) { f4_t z = {0.f, 0.f, 0.f, 0.f}; acc[mf][nf] = z; }

  const size_t inb = (size_t)b * (HI * WI) * CIN;
  size_t wg = (size_t)(oc0 + wrow) * 64 + (size_t)whalf * 32;
  for (int t = 0; t < 9; t++) {
    const int iy = py + (t / 3) - PAD;
    const int ix = pxx + (t % 3) - PAD;
    const bool val = prow_ok && iy >= 0 && iy < HI && ix >= 0 && ix < WI;
    const int pixoff = iy * WI + ix;
    for (int c = 0; c < CIN / 32; c++) {
      uint4 ah0 = {0,0,0,0}, ah1 = {0,0,0,0}, al0 = {0,0,0,0}, al1 = {0,0,0,0};
      if (val) {
        size_t a0 = inb + (size_t)pixoff * CIN + c * 32 + shalf * 16;
        const uint4* ph = (const uint4*)(inH + a0);
        const uint4* pl = (const uint4*)(inL + a0);
        ah0 = ph[0]; ah1 = ph[1]; al0 = pl[0]; al1 = pl[1];
      }
      uint4 wv0 = {0,0,0,0}, wv1 = {0,0,0,0}, wv2 = {0,0,0,0}, wv3 = {0,0,0,0};
      if (wact) {
        const uint4* q = (const uint4*)(w2 + wg);
        wv0 = q[0]; wv1 = q[1]; wv2 = q[2]; wv3 = q[3];
      }
      __syncthreads();
      *(uint4*)(la + awo0) = ah0;
      *(uint4*)(la + awo1) = ah1;
      *(uint4*)(la + awo2) = al0;
      *(uint4*)(la + awo3) = al1;
      if (wact) {
        *(uint4*)(lw + wwo[0]) = wv0;
        *(uint4*)(lw + wwo[1]) = wv1;
        *(uint4*)(lw + wwo[2]) = wv2;
        *(uint4*)(lw + wwo[3]) = wv3;
      }
      __syncthreads();
      bf8_t ah[MF], al[MF], wh[NF], wl[NF];
#pragma unroll
      for (int mf = 0; mf < MF; mf++) {
        ah[mf] = *(const bf8_t*)(la + aoh[mf]);
        al[mf] = *(const bf8_t*)(la + aol[mf]);
      }
#pragma unroll
      for (int nf = 0; nf < NF; nf++) {
        wh[nf] = *(const bf8_t*)(lw + woh[nf]);
        wl[nf] = *(const bf8_t*)(lw + wol[nf]);
      }
#pragma unroll
      for (int mf = 0; mf < MF; mf++)
#pragma unroll
        for (int nf = 0; nf < NF; nf++) {
          acc[mf][nf] = __builtin_amdgcn_mfma_f32_16x16x32_bf16(ah[mf], wh[nf], acc[mf][nf], 0, 0, 0);
          acc[mf][nf] = __builtin_amdgcn_mfma_f32_16x16x32_bf16(al[mf], wh[nf], acc[mf][nf], 0, 0, 0);
          acc[mf][nf] = __builtin_amdgcn_mfma_f32_16x16x32_bf16(ah[mf], wl[nf], acc[mf][nf], 0, 0, 0);
        }
      wg += (size_t)OCR * 64;
    }
  }

#pragma unroll
  for (int mf = 0; mf < MF; mf++) {
    const int pxb = px0 + wpx + mf * 16 + ((lane >> 4) << 2);
#pragma unroll
    for (int nf = 0; nf < NF; nf++) {
      const int oc = oc0 + woc + nf * 16 + (lane & 15);
      if (GATE) {
#pragma unroll
        for (int r = 0; r < 4; r++) {
          const int px = pxb + r;
          const int pyy = px >> 7, px2 = px & 127;
          const int iiy = (pyy * 62) >> 7, iix = (px2 * 62) >> 7;
          float gv = gA[((size_t)b * C2 + oc) * NPIX + px] +
                     gB[((size_t)b * C2 + oc) * 3844 + iiy * 62 + iix];
          float v = acc[mf][nf][r] * sigmoidf_(gv);
          u16 h = f2bf(v);
          u16 l = f2bf(v - bf2f(h));
          size_t o = ((size_t)b * NPIX + px) * C2 + oc;
          outH[o] = h;
          outL[o] = l;
        }
      } else {
        if (pxb < HO * WO && oc < OCTOT) {
          *(f4_t*)&outF[((size_t)b * OCTOT + oc) * (HO * WO) + pxb] = acc[mf][nf];
        }
      }
    }
  }
}

// ---------------- 1x1 conv as MFMA GEMM, direct-global fragments ----------------
// A: NHWC hi/lo [b][NPIX][128]; W: [Cout][128] hi/lo. Block: 128px x 128oc, 4 waves.
template<bool BIAS, bool SPLIT_OUT>
__global__ __launch_bounds__(256) void gemm1x1_k(const u16* __restrict__ inH,
                                                 const u16* __restrict__ inL,
                                                 const u16* __restrict__ wh,
                                                 const u16* __restrict__ wl,
                                                 const float* __restrict__ bias,
                                                 float* __restrict__ outF,
                                                 u16* __restrict__ outH, u16* __restrict__ outL) {
  const int b = blockIdx.z;
  const int nb0 = blockIdx.y * 128;
  const int px0 = blockIdx.x * 128;
  const int CoutTot = gridDim.y * 128;
  const int tid = threadIdx.x;
  const int lane = tid & 63, wid = tid >> 6;
  const int wpx = px0 + wid * 32;
  const int chunk = lane >> 4;

  f4_t acc[2][8];
#pragma unroll
  for (int mf = 0; mf < 2; mf++)
#pragma unroll
    for (int nf = 0; nf < 8; nf++) { f4_t z = {0.f, 0.f, 0.f, 0.f}; acc[mf][nf] = z; }

  size_t arow[2];
#pragma unroll
  for (int mf = 0; mf < 2; mf++)
    arow[mf] = ((size_t)b * NPIX + wpx + mf * 16 + (lane & 15)) * 128;
  size_t wrow[8];
#pragma unroll
  for (int nf = 0; nf < 8; nf++)
    wrow[nf] = (size_t)(nb0 + nf * 16 + (lane & 15)) * 128;

#pragma unroll
  for (int ks = 0; ks < 4; ks++) {
    const int ko = ks * 32 + chunk * 8;
    bf8_t ah[2], al[2], bh[8], bl[8];
#pragma unroll
    for (int mf = 0; mf < 2; mf++) {
      ah[mf] = *(const bf8_t*)(inH + arow[mf] + ko);
      al[mf] = *(const bf8_t*)(inL + arow[mf] + ko);
    }
#pragma unroll
    for (int nf = 0; nf < 8; nf++) {
      bh[nf] = *(const bf8_t*)(wh + wrow[nf] + ko);
      bl[nf] = *(const bf8_t*)(wl + wrow[nf] + ko);
    }
#pragma unroll
    for (int mf = 0; mf < 2; mf++)
#pragma unroll
      for (int nf = 0; nf < 8; nf++) {
        acc[mf][nf] = __builtin_amdgcn_mfma_f32_16x16x32_bf16(ah[mf], bh[nf], acc[mf][nf], 0, 0, 0);
        acc[mf][nf] = __builtin_amdgcn_mfma_f32_16x16x32_bf16(al[mf], bh[nf], acc[mf][nf], 0, 0, 0);
        acc[mf][nf] = __builtin_amdgcn_mfma_f32_16x16x32_bf16(ah[mf], bl[nf], acc[mf][nf], 0, 0, 0);
      }
  }

#pragma unroll
  for (int mf = 0; mf < 2; mf++) {
    const int pxq = wpx + mf * 16 + (lane >> 4) * 4;
#pragma unroll
    for (int nf = 0; nf < 8; nf++) {
      const int oc = nb0 + nf * 16 + (lane & 15);
      f4_t v = acc[mf][nf];
      if (BIAS) {
        float bv = bias[oc];
        v[0] += bv; v[1] += bv; v[2] += bv; v[3] += bv;
      }
      if (SPLIT_OUT) {
#pragma unroll
        for (int r = 0; r < 4; r++) {
          u16 h = f2bf(v[r]);
          size_t o = ((size_t)b * NPIX + pxq + r) * 128 + oc;
          outH[o] = h;
          outL[o] = f2bf(v[r] - bf2f(h));
        }
      } else {
        *(f4_t*)&outF[((size_t)b * CoutTot + oc) * NPIX + pxq] = v;
      }
    }
  }
}

// ---------------- fused modulated-deform-conv: gather + grouped MFMA GEMM ----------------
// Block: 128 px, one group g, 4 waves (2 M-frags each). K = 160 (9 taps x16ic + pad).
__global__ __launch_bounds__(256) void dgemm_k(const float* __restrict__ yt,
                                               const float* __restrict__ offs,
                                               const u16* __restrict__ wdh,
                                               const u16* __restrict__ wdl,
                                               const float* __restrict__ dbias,
                                               u16* __restrict__ featH, u16* __restrict__ featL) {
  const int b = blockIdx.z, g = blockIdx.y;
  const int px0 = blockIdx.x * 128;
  const int tid = threadIdx.x;
  const int lane = tid & 63, wid = tid >> 6;
  const int chunk = lane >> 4;        // 0..3 : k-octet
  const int thalf = chunk >> 1;       // tap parity within K-step
  const int ic0 = (chunk & 1) * 8;    // input-channel octet
  const float* yb = yt + (size_t)b * NPIX * C1;
  const float* ob = offs + (size_t)b * 18 * NPIX;

  int pm[2];
  float pyb[2], pxb[2];
#pragma unroll
  for (int mf = 0; mf < 2; mf++) {
    pm[mf] = px0 + wid * 32 + mf * 16 + (lane & 15);
    pyb[mf] = (float)(pm[mf] >> 7);
    pxb[mf] = (float)(pm[mf] & 127);
  }

  f4_t acc[2];
  { f4_t z = {0.f, 0.f, 0.f, 0.f}; acc[0] = z; acc[1] = z; }

  const size_t wbase = (size_t)(g * 16 + (lane & 15)) * 160;
#pragma unroll
  for (int s = 0; s < 5; s++) {
    bf8_t ah[2], al[2];
#pragma unroll
    for (int mf = 0; mf < 2; mf++) {
      int t = 2 * s + thalf;
      int teff = t > 8 ? 8 : t;
      float dy = ob[(size_t)(2 * teff) * NPIX + pm[mf]];
      float dx = ob[(size_t)(2 * teff + 1) * NPIX + pm[mf]];
      float mk = sigmoidf_(ob[(size_t)teff * NPIX + pm[mf]]);
      int ky = teff / 3, kx = teff - 3 * ky;
      float pyf = pyb[mf] - 1.f + (float)ky + dy;
      float pxf = pxb[mf] - 1.f + (float)kx + dx;
      float y0f = floorf(pyf), x0f = floorf(pxf);
      float fy = pyf - y0f, fx = pxf - x0f;
      int y0 = (int)y0f, x0 = (int)x0f;
      int y1 = y0 + 1, x1 = x0 + 1;
      float w00 = (1.f - fy) * (1.f - fx) * mk;
      float w01 = (1.f - fy) * fx * mk;
      float w10 = fy * (1.f - fx) * mk;
      float w11 = fy * fx * mk;
      bool vy0 = (y0 >= 0 && y0 < HH), vy1 = (y1 >= 0 && y1 < HH);
      bool vx0 = (x0 >= 0 && x0 < WW), vx1 = (x1 >= 0 && x1 < WW);
      if (!(vy0 && vx0)) w00 = 0.f;
      if (!(vy0 && vx1)) w01 = 0.f;
      if (!(vy1 && vx0)) w10 = 0.f;
      if (!(vy1 && vx1)) w11 = 0.f;
      int cy0 = min(max(y0, 0), HH - 1), cy1 = min(max(y1, 0), HH - 1);
      int cx0 = min(max(x0, 0), WW - 1), cx1 = min(max(x1, 0), WW - 1);
      const float* p00 = yb + ((size_t)(cy0 * WW + cx0)) * C1 + g * 16 + ic0;
      const float* p01 = yb + ((size_t)(cy0 * WW + cx1)) * C1 + g * 16 + ic0;
      const float* p10 = yb + ((size_t)(cy1 * WW + cx0)) * C1 + g * 16 + ic0;
      const float* p11 = yb + ((size_t)(cy1 * WW + cx1)) * C1 + g * 16 + ic0;
      float4 a00 = *(const float4*)p00, b00 = *(const float4*)(p00 + 4);
      float4 a01 = *(const float4*)p01, b01 = *(const float4*)(p01 + 4);
      float4 a10 = *(const float4*)p10, b10 = *(const float4*)(p10 + 4);
      float4 a11 = *(const float4*)p11, b11 = *(const float4*)(p11 + 4);
      float sv[8];
      sv[0] = w00 * a00.x + w01 * a01.x + w10 * a10.x + w11 * a11.x;
      sv[1] = w00 * a00.y + w01 * a01.y + w10 * a10.y + w11 * a11.y;
      sv[2] = w00 * a00.z + w01 * a01.z + w10 * a10.z + w11 * a11.z;
      sv[3] = w00 * a00.w + w01 * a01.w + w10 * a10.w + w11 * a11.w;
      sv[4] = w00 * b00.x + w01 * b01.x + w10 * b10.x + w11 * b11.x;
      sv[5] = w00 * b00.y + w01 * b01.y + w10 * b10.y + w11 * b11.y;
      sv[6] = w00 * b00.z + w01 * b01.z + w10 * b10.z + w11 * b11.z;
      sv[7] = w00 * b00.w + w01 * b01.w + w10 * b10.w + w11 * b11.w;
      bf8_t hh, ll;
#pragma unroll
      for (int j = 0; j < 8; j++) {
        u16 h = f2bf(sv[j]);
        hh[j] = (short)h;
        ll[j] = (short)f2bf(sv[j] - bf2f(h));
      }
      ah[mf] = hh;
      al[mf] = ll;
    }
    const int ko = s * 32 + chunk * 8;
    bf8_t wh = *(const bf8_t*)(wdh + wbase + ko);
    bf8_t wl = *(const bf8_t*)(wdl + wbase + ko);
#pragma unroll
    for (int mf = 0; mf < 2; mf++) {
      acc[mf] = __builtin_amdgcn_mfma_f32_16x16x32_bf16(ah[mf], wh, acc[mf], 0, 0, 0);
      acc[mf] = __builtin_amdgcn_mfma_f32_16x16x32_bf16(al[mf], wh, acc[mf], 0, 0, 0);
      acc[mf] = __builtin_amdgcn_mfma_f32_16x16x32_bf16(ah[mf], wl, acc[mf], 0, 0, 0);
    }
  }

  const int oc = g * 16 + (lane & 15);
  const float bv = dbias[oc];
#pragma unroll
  for (int mf = 0; mf < 2; mf++) {
    const int pxq = px0 + wid * 32 + mf * 16 + (lane >> 4) * 4;
#pragma unroll
    for (int r = 0; r < 4; r++) {
      float v = fmaxf(acc[mf][r] + bv, 0.f);  // bias + relu (pw input)
      u16 h = f2bf(v);
      size_t o = ((size_t)b * NPIX + pxq + r) * 128 + oc;
      featH[o] = h;
      featL[o] = f2bf(v - bf2f(h));
    }
  }
}

// ---------------- depthwise 3x3, pad=1 ----------------
__global__ __launch_bounds__(256) void dw3x3_k(const float* __restrict__ in,
                                               const float* __restrict__ w,
                                               float* __restrict__ out, int Cc) {
  int idx = blockIdx.x * 256 + threadIdx.x;
  int total = NB * Cc * NPIX;
  if (idx >= total) return;
  int n = idx & (NPIX - 1);
  int bc = idx >> 14;
  int c = bc % Cc;
  int yy = n >> 7, xx = n & 127;
  const float* p = in + (size_t)bc * NPIX;
  const float* wc = w + c * 9;
  float acc = 0.f;
#pragma unroll
  for (int ky = 0; ky < 3; ky++) {
    int iy = yy + ky - 1;
    if (iy < 0 || iy >= HH) continue;
#pragma unroll
    for (int kx = 0; kx < 3; kx++) {
      int ix = xx + kx - 1;
      if (ix < 0 || ix >= WW) continue;
      acc += wc[ky * 3 + kx] * p[iy * WW + ix];
    }
  }
  out[idx] = acc;
}

// ---------------- zero small accumulators ----------------
__global__ void zero_k(float* p, int n) {
  int i = blockIdx.x * 256 + threadIdx.x;
  if (i < n) p[i] = 0.f;
}

// ---------------- attention: partial Gram + sumsq ----------------
__global__ __launch_bounds__(256) void attn_partial_k(const float* __restrict__ qbuf,
                                                      const float* __restrict__ kvbuf,
                                                      float* __restrict__ s_acc,
                                                      float* __restrict__ qss,
                                                      float* __restrict__ kss) {
  __shared__ float qs[16][129];
  __shared__ float ks[16][129];
  int b = blockIdx.z, h = blockIdx.y, seg = blockIdx.x;
  int tid = threadIdx.x;
  int dd = tid & 15, cc = tid >> 4;
  int n_start = seg * (NPIX / 16);
  float acc = 0.f, q2 = 0.f, k2s = 0.f;
  const float* qb = qbuf + ((size_t)b * C1 + h * DH) * NPIX;
  const float* kb = kvbuf + ((size_t)b * C2 + h * DH) * NPIX;
  for (int n0 = n_start; n0 < n_start + NPIX / 16; n0 += 128) {
    for (int e = tid; e < 16 * 128; e += 256) {
      int r = e >> 7, col = e & 127;
      qs[r][col] = qb[(size_t)r * NPIX + n0 + col];
      ks[r][col] = kb[(size_t)r * NPIX + n0 + col];
    }
    __syncthreads();
#pragma unroll 8
    for (int j = 0; j < 128; j++) {
      float qv = qs[cc][j], kv = ks[dd][j];
      acc += qv * kv;
      q2 += qv * qv;
      k2s += kv * kv;
    }
    __syncthreads();
  }
  int bh = b * NHEADS + h;
  atomicAdd(&s_acc[((size_t)bh * 16 + cc) * 16 + dd], acc);
  if (dd == 0) atomicAdd(&qss[bh * 16 + cc], q2);
  if (cc == 0) atomicAdd(&kss[bh * 16 + dd], k2s);
}

// ---------------- attention: normalize + softmax ----------------
__global__ __launch_bounds__(256) void attn_final_k(const float* __restrict__ s_acc,
                                                    const float* __restrict__ qss,
                                                    const float* __restrict__ kss,
                                                    const float* __restrict__ temp,
                                                    float* __restrict__ attn) {
  __shared__ float S[16][17];
  __shared__ float qn[16], kn[16];
  int bh = blockIdx.x;
  int h = bh % NHEADS;
  int tid = threadIdx.x;
  int dd = tid & 15, cc = tid >> 4;
  if (tid < 16) {
    qn[tid] = fmaxf(sqrtf(qss[bh * 16 + tid]), 1e-12f);
    kn[tid] = fmaxf(sqrtf(kss[bh * 16 + tid]), 1e-12f);
  }
  __syncthreads();
  float t = temp[h];
  float s = s_acc[((size_t)bh * 16 + cc) * 16 + dd] / (qn[cc] * kn[dd]) * t;
  S[cc][dd] = s;
  __syncthreads();
  float mx = -1e30f;
#pragma unroll
  for (int j = 0; j < 16; j++) mx = fmaxf(mx, S[cc][j]);
  float sum = 0.f;
#pragma unroll
  for (int j = 0; j < 16; j++) sum += expf(S[cc][j] - mx);
  attn[((size_t)bh * 16 + cc) * 16 + dd] = expf(s - mx) / sum;
}

// ---------------- attention: out = attn @ v -> NHWC hi/lo ----------------
__global__ __launch_bounds__(256) void attnout_k(const float* __restrict__ attn,
                                                 const float* __restrict__ kvbuf,
                                                 u16* __restrict__ outH, u16* __restrict__ outL) {
  __shared__ float s_a[16][16];
  int b = blockIdx.z, h = blockIdx.y;
  int tid = threadIdx.x;
  int bh = b * NHEADS + h;
  s_a[tid >> 4][tid & 15] = attn[((size_t)bh * 16 + (tid >> 4)) * 16 + (tid & 15)];
  __syncthreads();
  int n = blockIdx.x * 256 + tid;
  const float* vb = kvbuf + ((size_t)b * C2 + C1 + h * DH) * NPIX;
  float acc[16];
#pragma unroll
  for (int c = 0; c < 16; c++) acc[c] = 0.f;
#pragma unroll
  for (int d = 0; d < 16; d++) {
    float vv = vb[(size_t)d * NPIX + n];
#pragma unroll
    for (int c = 0; c < 16; c++) acc[c] += s_a[c][d] * vv;
  }
  unsigned wh[8], wlv[8];
#pragma unroll
  for (int c = 0; c < 8; c++) {
    u16 h0 = f2bf(acc[2 * c]);
    u16 h1 = f2bf(acc[2 * c + 1]);
    u16 l0 = f2bf(acc[2 * c] - bf2f(h0));
    u16 l1 = f2bf(acc[2 * c + 1] - bf2f(h1));
    wh[c] = (unsigned)h0 | ((unsigned)h1 << 16);
    wlv[c] = (unsigned)l0 | ((unsigned)l1 << 16);
  }
  size_t base = ((size_t)b * NPIX + n) * 128 + h * 16;
  uint4* ph = (uint4*)(outH + base);
  uint4* pl = (uint4*)(outL + base);
  ph[0] = make_uint4(wh[0], wh[1], wh[2], wh[3]);
  ph[1] = make_uint4(wh[4], wh[5], wh[6], wh[7]);
  pl[0] = make_uint4(wlv[0], wlv[1], wlv[2], wlv[3]);
  pl[1] = make_uint4(wlv[4], wlv[5], wlv[6], wlv[7]);
}

extern "C" void kernel_launch(void* const* d_in, const int* in_sizes, int n_in,
                              void* d_out, int out_size, void* d_ws, size_t ws_size,
                              hipStream_t stream) {
  const float* x = (const float*)d_in[0];
  const float* y = (const float*)d_in[1];
  const float* q_w = (const float*)d_in[2];
  const float* qd_w = (const float*)d_in[3];
  const float* kv_w = (const float*)d_in[4];
  const float* kvd_w = (const float*)d_in[5];
  const float* proj_w = (const float*)d_in[6];
  const float* temperature = (const float*)d_in[7];
  const float* k2_w = (const float*)d_in[8];
  const float* k3_w = (const float*)d_in[9];
  const float* k4_w = (const float*)d_in[10];
  const float* dcn_w = (const float*)d_in[11];
  const float* dcn_b = (const float*)d_in[12];
  const float* pw_w = (const float*)d_in[13];
  const float* pw_b = (const float*)d_in[14];
  float* out = (float*)d_out;

  char* ws = (char*)d_ws;
  size_t off = 0;
  auto alloc = [&](size_t nbytes) {
    char* p = ws + off;
    off += (nbytes + 255) & ~(size_t)255;
    return p;
  };
  float* CAT = (float*)alloc((size_t)NB * C2 * NPIX * 4);            // also KV1
  u16* CATH = (u16*)alloc((size_t)NB * NPIX * C2 * 2);               // also XH, KVb(0)
  u16* CATL = (u16*)alloc((size_t)NB * NPIX * C2 * 2);               // also XL, KVb(1)
  u16* PH = (u16*)alloc((size_t)NB * 4096 * C2 * 2);
  u16* PL = (u16*)alloc((size_t)NB * 4096 * C2 * 2);
  float* A2 = (float*)alloc((size_t)NB * C2 * 3844 * 4);
  u16* OUT3H = (u16*)alloc((size_t)NB * NPIX * C2 * 2 * 2);          // H then L; also QT1, FEAT, AO
  u16* OUT3L = OUT3H + (size_t)NB * NPIX * C2;
  float* OFFS = (float*)alloc((size_t)NB * 18 * NPIX * 4);
  float* YT = (float*)alloc((size_t)NB * NPIX * C1 * 4);             // also ALH/ALL
  float* Qb = (float*)alloc((size_t)NB * C1 * NPIX * 4);
  u16* W2K2 = (u16*)alloc((size_t)9 * 8 * 256 * 64 * 2);
  u16* W2K3 = (u16*)alloc((size_t)9 * 8 * 256 * 64 * 2);
  u16* W2K4 = (u16*)alloc((size_t)9 * 8 * 32 * 64 * 2);
  u16* WDH = (u16*)alloc((size_t)128 * 160 * 2);
  u16* WDL = (u16*)alloc((size_t)128 * 160 * 2);
  u16* WQH = (u16*)alloc((size_t)128 * 128 * 2);
  u16* WQL = (u16*)alloc((size_t)128 * 128 * 2);
  u16* WPWH = (u16*)alloc((size_t)128 * 128 * 2);
  u16* WPWL = (u16*)alloc((size_t)128 * 128 * 2);
  u16* WKVH = (u16*)alloc((size_t)256 * 128 * 2);
  u16* WKVL = (u16*)alloc((size_t)256 * 128 * 2);
  u16* WPJH = (u16*)alloc((size_t)128 * 128 * 2);
  u16* WPJL = (u16*)alloc((size_t)128 * 128 * 2);
  float* SACC = (float*)alloc((size_t)(NB * NHEADS * 256 + 512 + NB * NHEADS * 256) * 4);
  float* QSS = SACC + NB * NHEADS * 256;
  float* KSS = QSS + 256;
  float* ATTN = KSS + 256;

  // region reuse
  u16* XH = CATH;                                    // x NHWC split (dead before CAT split)
  u16* XL = CATL;
  float* QT1 = (float*)OUT3H;                        // q 1x1 out (dead before k3 writes OUT3)
  u16* FEATH = OUT3H;                                // deform out (after k4 consumed OUT3)
  u16* FEATL = OUT3L;
  u16* ALH = (u16*)YT;                               // aligned split (after dgemm consumed YT)
  u16* ALL = ALH + (size_t)NB * NPIX * C1;
  float* KV1 = CAT;                                  // kv 1x1 out (after k3 consumed CAT gate)
  float* KVb = (float*)CATH;                         // kv dw out (CATH+CATL contiguous 33.5MB)
  u16* AOH = OUT3H;                                  // attn out split (after pw consumed FEAT)
  u16* AOL = OUT3L;

  dim3 blk(256);

  // weight prep
  w1trans_k<<<dim3(64), blk, 0, stream>>>(q_w, WQH, WQL, 128 * 128);
  w1trans_k<<<dim3(64), blk, 0, stream>>>(pw_w, WPWH, WPWL, 128 * 128);
  w1trans_k<<<dim3(128), blk, 0, stream>>>(kv_w, WKVH, WKVL, 256 * 128);
  w1trans_k<<<dim3(64), blk, 0, stream>>>(proj_w, WPJH, WPJL, 128 * 128);
  wdprep_k<<<dim3(80), blk, 0, stream>>>(dcn_w, WDH, WDL);
  wtrans_k<<<dim3((9 * 256 * 256 + 255) / 256), blk, 0, stream>>>(k2_w, W2K2, 256, 256);
  wtrans_k<<<dim3((9 * 256 * 256 + 255) / 256), blk, 0, stream>>>(k3_w, W2K3, 256, 256);
  wtrans_k<<<dim3((9 * 256 * 32 + 255) / 256), blk, 0, stream>>>(k4_w, W2K4, 18, 32);

  // q path: x -> NHWC split -> 1x1 MFMA -> depthwise
  nhwc_split_k<C1><<<dim3(NPIX / 64, 2, NB), blk, 0, stream>>>(x, XH, XL, NPIX);
  gemm1x1_k<false, false><<<dim3(NPIX / 128, 1, NB), blk, 0, stream>>>(
      XH, XL, WQH, WQL, nullptr, QT1, nullptr, nullptr);
  dw3x3_k<<<dim3((NB * C1 * NPIX + 255) / 256), blk, 0, stream>>>(QT1, qd_w, Qb, C1);

  // offset head
  concat_k<<<dim3((NB * C2 * NPIX / 4 + 255) / 256), blk, 0, stream>>>(y, x, CAT);
  nhwc_split_k<C2><<<dim3(NPIX / 64, C2 / 64, NB), blk, 0, stream>>>(CAT, CATH, CATL, NPIX);
  avgpool_split_k<<<dim3(4096 / 64, C2 / 64, NB), blk, 0, stream>>>(CAT, PH, PL);
  convmfma_k<128, 62, 62, 64, 64, 0, 256, 256, false>
      <<<dim3(31, 2, NB), blk, 0, stream>>>(PH, PL, W2K2, nullptr, nullptr, A2, nullptr, nullptr);
  convmfma_k<128, 128, 128, 128, 128, 1, 256, 256, true>
      <<<dim3(128, 2, NB), blk, 0, stream>>>(CATH, CATL, W2K3, CAT, A2, nullptr, OUT3H, OUT3L);
  convmfma_k<32, 128, 128, 128, 128, 1, 18, 32, false>
      <<<dim3(128, 1, NB), blk, 0, stream>>>(OUT3H, OUT3L, W2K4, nullptr, nullptr, OFFS, nullptr, nullptr);

  // deformable alignment: y -> NHWC, fused gather+grouped-GEMM, then pw 1x1
  ytrans_k<<<dim3(NPIX / 64, 2, NB), blk, 0, stream>>>(y, YT);
  dgemm_k<<<dim3(NPIX / 128, NG, NB), blk, 0, stream>>>(YT, OFFS, WDH, WDL, dcn_b, FEATH, FEATL);
  gemm1x1_k<true, true><<<dim3(NPIX / 128, 1, NB), blk, 0, stream>>>(
      FEATH, FEATL, WPWH, WPWL, pw_b, nullptr, ALH, ALL);

  // kv path
  gemm1x1_k<false, false><<<dim3(NPIX / 128, 2, NB), blk, 0, stream>>>(
      ALH, ALL, WKVH, WKVL, nullptr, KV1, nullptr, nullptr);
  dw3x3_k<<<dim3((NB * C2 * NPIX + 255) / 256), blk, 0, stream>>>(KV1, kvd_w, KVb, C2);

  // attention
  zero_k<<<dim3((4608 + 255) / 256), blk, 0, stream>>>(SACC, 4608);
  attn_partial_k<<<dim3(16, NHEADS, NB), blk, 0, stream>>>(Qb, KVb, SACC, QSS, KSS);
  attn_final_k<<<dim3(NB * NHEADS), blk, 0, stream>>>(SACC, QSS, KSS, temperature, ATTN);
  attnout_k<<<dim3(NPIX / 256, NHEADS, NB), blk, 0, stream>>>(ATTN, KVb, AOH, AOL);
  gemm1x1_k<false, false><<<dim3(NPIX / 128, 1, NB), blk, 0, stream>>>(
      AOH, AOL, WPJH, WPJL, nullptr, out, nullptr, nullptr);
}